// Round 1
// baseline (641.666 us; speedup 1.0000x reference)
//
#include <hip/hip_runtime.h>

#define N_ 16
#define T_ 1024
#define E_ 1024
#define H_ 256
#define MAXOUT 4096

// ---------------- workspace layout (float units) ----------------
constexpr size_t OFF_MASK = 0;                                   // N*T floats
constexpr size_t OFF_B1   = OFF_MASK + (size_t)N_ * T_;          // 3*E*H floats
constexpr size_t OFF_B2   = OFF_B1 + 3ull * E_ * H_;             // 3*H*H floats
constexpr size_t OFF_X1   = OFF_B2 + 3ull * H_ * H_;             // N*T*H floats
constexpr size_t OFF_X2   = OFF_X1 + (size_t)N_ * T_ * H_;       // N*T*H floats
constexpr size_t OFF_DUR  = OFF_X2 + (size_t)N_ * T_ * H_;       // N*T ints
constexpr size_t OFF_CUM  = OFF_DUR + (size_t)N_ * T_;           // N*T ints
// total ~9.42M floats ~= 37.7 MB

// ---------------- mask prep (dtype-robust) ----------------
// padding_mask[0][1] is guaranteed true (lens >= T/2 = 512).
// bool-byte storage  -> raw[1] == 1
// int32/float32      -> raw[1] == 0 ; then read 4-byte words, nonzero -> 1.0
__global__ void prep_mask_kernel(const unsigned char* __restrict__ raw,
                                 float* __restrict__ maskf) {
    int i = blockIdx.x * 256 + threadIdx.x;
    if (i >= N_ * T_) return;
    bool bytefmt = (raw[1] == 1);
    float v;
    if (bytefmt) {
        v = (raw[i] != 0) ? 1.0f : 0.0f;
    } else {
        const int* wi = reinterpret_cast<const int*>(raw);
        v = (wi[i] != 0) ? 1.0f : 0.0f;
    }
    maskf[i] = v;
}

// ---------------- weight transpose: w[h][e][k] -> Bt[k*EIN+e][h] ----------------
template <int EIN>
__global__ void transp_w_kernel(const float* __restrict__ w,
                                float* __restrict__ Bt) {
    int i = blockIdx.x * 256 + threadIdx.x;   // grid sized exactly
    int c = i >> 8;          // / H_
    int h = i & (H_ - 1);
    int k = c / EIN;
    int e = c % EIN;
    Bt[i] = w[(size_t)h * EIN * 3 + (size_t)e * 3 + k];
}

// ---------------- conv-as-GEMM: Y[m][h] = relu(sum_c A[m][c]*Bt[c][h] + bias[h]) ----------------
// A[m=(n,t)][c=(k,e)] = X[n][t+k-1][e] (* mask), zero-padded in t.
template <int EIN>
__global__ __launch_bounds__(256) void conv_gemm_kernel(
    const float* __restrict__ X,     // [N_][T_][EIN]
    const float* __restrict__ Bt,    // [3*EIN][H_]
    const float* __restrict__ bias,  // [H_]
    const float* __restrict__ mask,  // [N_*T_] or nullptr
    float* __restrict__ Y)           // [N_*T_][H_]
{
    constexpr int KDIM = 3 * EIN;
    __shared__ __align__(16) float As[16][68];
    __shared__ __align__(16) float Bs[16][68];

    const int m0 = blockIdx.x * 64;
    const int n  = m0 >> 10;
    const int t0 = m0 & (T_ - 1);
    const int h0 = blockIdx.y * 64;
    const int tid = threadIdx.x;
    const int tx = tid & 15;        // h sub-tile
    const int ty = tid >> 4;        // m sub-tile
    const int ar = tid >> 2;        // A-load row 0..63
    const int ac = (tid & 3) * 4;   // A-load col 0..12
    const int br = tid >> 4;        // B-load row 0..15
    const int bc = (tid & 15) * 4;  // B-load col 0..60

    float acc[4][4] = {};

    for (int c0 = 0; c0 < KDIM; c0 += 16) {
        const int k  = c0 / EIN;        // uniform within BK tile (EIN % 16 == 0)
        const int e0 = c0 % EIN;
        // ---- load A tile (64 x 16), im2col on the fly ----
        const int tt = t0 + ar + k - 1;
        float4 av = make_float4(0.f, 0.f, 0.f, 0.f);
        if (tt >= 0 && tt < T_) {
            const float* p = X + ((size_t)(n * T_ + tt) * EIN + e0 + ac);
            av = *reinterpret_cast<const float4*>(p);
            if (mask) {
                float mv = mask[n * T_ + tt];
                av.x *= mv; av.y *= mv; av.z *= mv; av.w *= mv;
            }
        }
        As[ac + 0][ar] = av.x;
        As[ac + 1][ar] = av.y;
        As[ac + 2][ar] = av.z;
        As[ac + 3][ar] = av.w;
        // ---- load B tile (16 x 64) ----
        *reinterpret_cast<float4*>(&Bs[br][bc]) =
            *reinterpret_cast<const float4*>(Bt + (size_t)(c0 + br) * H_ + h0 + bc);
        __syncthreads();

        // ---- compute: two-level accumulation (per-tile partial) to keep
        //      summation error close to numpy's pairwise sums ----
        float pacc[4][4] = {};
#pragma unroll
        for (int kk = 0; kk < 16; ++kk) {
            float4 a = *reinterpret_cast<const float4*>(&As[kk][ty * 4]);
            float4 b = *reinterpret_cast<const float4*>(&Bs[kk][tx * 4]);
            float aa[4] = {a.x, a.y, a.z, a.w};
            float bb[4] = {b.x, b.y, b.z, b.w};
#pragma unroll
            for (int i = 0; i < 4; ++i)
#pragma unroll
                for (int j = 0; j < 4; ++j)
                    pacc[i][j] = fmaf(aa[i], bb[j], pacc[i][j]);
        }
#pragma unroll
        for (int i = 0; i < 4; ++i)
#pragma unroll
            for (int j = 0; j < 4; ++j)
                acc[i][j] += pacc[i][j];
        __syncthreads();
    }

    // ---- epilogue: bias + relu, float4 stores ----
#pragma unroll
    for (int i = 0; i < 4; ++i) {
        const int m = m0 + ty * 4 + i;
        float* orow = Y + (size_t)m * H_ + h0 + tx * 4;
        float4 o;
        o.x = fmaxf(acc[i][0] + bias[h0 + tx * 4 + 0], 0.f);
        o.y = fmaxf(acc[i][1] + bias[h0 + tx * 4 + 1], 0.f);
        o.z = fmaxf(acc[i][2] + bias[h0 + tx * 4 + 2], 0.f);
        o.w = fmaxf(acc[i][3] + bias[h0 + tx * 4 + 3], 0.f);
        *reinterpret_cast<float4*>(orow) = o;
    }
}

// ---------------- LayerNorm (in-place) * mask ----------------
__global__ __launch_bounds__(256) void ln_mask_kernel(
    float* __restrict__ X,           // [rows][H_], in-place
    const float* __restrict__ g, const float* __restrict__ b,
    const float* __restrict__ mask)  // [rows]
{
    const int row = blockIdx.x;
    const int h = threadIdx.x;
    float v = X[(size_t)row * H_ + h];
    float s = v, ss = v * v;
#pragma unroll
    for (int off = 32; off; off >>= 1) {
        s  += __shfl_down(s, off);
        ss += __shfl_down(ss, off);
    }
    __shared__ float shs[4], shss[4];
    const int wid = h >> 6, lane = h & 63;
    if (lane == 0) { shs[wid] = s; shss[wid] = ss; }
    __syncthreads();
    const float S  = shs[0] + shs[1] + shs[2] + shs[3];
    const float SS = shss[0] + shss[1] + shss[2] + shss[3];
    const float mu  = S * (1.0f / H_);
    const float var = SS * (1.0f / H_) - mu * mu;
    const float inv = 1.0f / sqrtf(var + 1e-5f);
    const float y = (v - mu) * inv * g[h] + b[h];
    X[(size_t)row * H_ + h] = y * mask[row];
}

// ---------------- LayerNorm + projection + duration ----------------
__global__ __launch_bounds__(256) void ln_proj_dur_kernel(
    const float* __restrict__ X,     // [rows][H_]
    const float* __restrict__ g, const float* __restrict__ b,
    const float* __restrict__ pw, const float* __restrict__ pb,
    const float* __restrict__ mask,
    int* __restrict__ dur)           // [rows]
{
    const int row = blockIdx.x;
    const int h = threadIdx.x;
    float v = X[(size_t)row * H_ + h];
    float s = v, ss = v * v;
#pragma unroll
    for (int off = 32; off; off >>= 1) {
        s  += __shfl_down(s, off);
        ss += __shfl_down(ss, off);
    }
    __shared__ float shs[4], shss[4], shc[4];
    const int wid = h >> 6, lane = h & 63;
    if (lane == 0) { shs[wid] = s; shss[wid] = ss; }
    __syncthreads();
    const float S  = shs[0] + shs[1] + shs[2] + shs[3];
    const float SS = shss[0] + shss[1] + shss[2] + shss[3];
    const float mu  = S * (1.0f / H_);
    const float var = SS * (1.0f / H_) - mu * mu;
    const float inv = 1.0f / sqrtf(var + 1e-5f);
    const float y = (v - mu) * inv * g[h] + b[h];
    float c = y * pw[h];
#pragma unroll
    for (int off = 32; off; off >>= 1) c += __shfl_down(c, off);
    if (lane == 0) shc[wid] = c;
    __syncthreads();
    if (h == 0) {
        const float ld = shc[0] + shc[1] + shc[2] + shc[3] + pb[0];
        const float dv = rintf(expf(ld) - 1.0f);   // round half-to-even, like jnp.round
        int di = (int)dv;
        if (di < 0) di = 0;
        if (mask[row] == 0.0f) di = 0;
        dur[row] = di;
    }
}

// ---------------- per-sequence inclusive cumsum (T=1024) ----------------
__global__ __launch_bounds__(1024) void cumsum_kernel(
    const int* __restrict__ dur, int* __restrict__ cum,
    float* __restrict__ seq_lens_out)   // tail of d_out, float32
{
    __shared__ int s[1024];
    const int n = blockIdx.x, t = threadIdx.x;
    s[t] = dur[n * T_ + t];
    __syncthreads();
    for (int off = 1; off < 1024; off <<= 1) {
        int v = (t >= off) ? s[t - off] : 0;
        __syncthreads();
        s[t] += v;
        __syncthreads();
    }
    cum[n * T_ + t] = s[t];
    if (t == T_ - 1) seq_lens_out[n] = (float)s[t];
}

// ---------------- length-regulator upsample ----------------
__global__ __launch_bounds__(256) void upsample_kernel(
    const float* __restrict__ seqs,  // [N_][T_][E_]
    const int* __restrict__ cum,     // [N_][T_]
    float* __restrict__ out)         // [N_][MAXOUT][E_]
{
    const int bp = blockIdx.x;           // n*MAXOUT + p
    const int n = bp >> 12;
    const int p = bp & (MAXOUT - 1);
    __shared__ int sh_idx, sh_valid;
    if (threadIdx.x == 0) {
        const int* c = cum + n * T_;
        const int slen = c[T_ - 1];
        int lo = 0, hi = T_;
        while (lo < hi) {                 // upper_bound: first idx with c[idx] > p
            int mid = (lo + hi) >> 1;
            if (c[mid] <= p) lo = mid + 1; else hi = mid;
        }
        sh_idx = (lo < T_ - 1) ? lo : (T_ - 1);
        sh_valid = (p < slen) ? 1 : 0;
    }
    __syncthreads();
    const int idx = sh_idx;
    float4 v = make_float4(0.f, 0.f, 0.f, 0.f);
    if (sh_valid) {
        const float4* src = reinterpret_cast<const float4*>(
            seqs + ((size_t)(n * T_ + idx) * E_));
        v = src[threadIdx.x];
    }
    reinterpret_cast<float4*>(out + (size_t)bp * E_)[threadIdx.x] = v;
}

// ---------------- launch ----------------
extern "C" void kernel_launch(void* const* d_in, const int* in_sizes, int n_in,
                              void* d_out, int out_size, void* d_ws, size_t ws_size,
                              hipStream_t stream) {
    const float* seqs = (const float*)d_in[0];
    const float* w1   = (const float*)d_in[1];
    const float* b1   = (const float*)d_in[2];
    const float* g1   = (const float*)d_in[3];
    const float* bb1  = (const float*)d_in[4];
    const float* w2   = (const float*)d_in[5];
    const float* b2   = (const float*)d_in[6];
    const float* g2   = (const float*)d_in[7];
    const float* bb2  = (const float*)d_in[8];
    const float* pw   = (const float*)d_in[9];
    const float* pb   = (const float*)d_in[10];
    const unsigned char* mraw = (const unsigned char*)d_in[11];

    float* ws   = (float*)d_ws;
    float* maskf = ws + OFF_MASK;
    float* B1t   = ws + OFF_B1;
    float* B2t   = ws + OFF_B2;
    float* X1    = ws + OFF_X1;
    float* X2    = ws + OFF_X2;
    int*   dur   = (int*)(ws + OFF_DUR);
    int*   cum   = (int*)(ws + OFF_CUM);

    float* out      = (float*)d_out;
    float* slen_out = out + (size_t)N_ * MAXOUT * E_;  // tuple output 1

    prep_mask_kernel<<<(N_ * T_) / 256, 256, 0, stream>>>(mraw, maskf);
    transp_w_kernel<E_><<<3 * E_, 256, 0, stream>>>(w1, B1t);
    transp_w_kernel<H_><<<3 * H_, 256, 0, stream>>>(w2, B2t);

    // conv1 (E=1024 -> H=256) + bias + relu
    conv_gemm_kernel<E_><<<dim3((N_ * T_) / 64, H_ / 64), 256, 0, stream>>>(
        seqs, B1t, b1, maskf, X1);
    // ln1 * mask (in place)
    ln_mask_kernel<<<N_ * T_, 256, 0, stream>>>(X1, g1, bb1, maskf);
    // conv2 (H -> H) + bias + relu
    conv_gemm_kernel<H_><<<dim3((N_ * T_) / 64, H_ / 64), 256, 0, stream>>>(
        X1, B2t, b2, nullptr, X2);
    // ln2 + proj + duration
    ln_proj_dur_kernel<<<N_ * T_, 256, 0, stream>>>(X2, g2, bb2, pw, pb, maskf, dur);
    // cumsum + seq_lens
    cumsum_kernel<<<N_, 1024, 0, stream>>>(dur, cum, slen_out);
    // upsample/gather
    upsample_kernel<<<N_ * MAXOUT, 256, 0, stream>>>(seqs, cum, out);
}

// Round 2
// 270.757 us; speedup vs baseline: 2.3699x; 2.3699x over previous
//
#include <hip/hip_runtime.h>

#define N_ 16
#define T_ 1024
#define E_ 1024
#define H_ 256
#define MAXOUT 4096
#define M_ (N_ * T_)          // 16384 rows
#define NJ 768                // 3*H_ GEMM output cols
#define NJ16 48               // NJ/16

typedef _Float16 half_t;
typedef __attribute__((ext_vector_type(8))) _Float16 f16x8;
typedef __attribute__((ext_vector_type(4))) float f32x4;

// ---------------- d_out scratch layout (bytes) ----------------
// upsample (last kernel) rewrites the entire main output region.
constexpr size_t Y1_OFF  = 0;                       // 16384*768*4  = 50331648
constexpr size_t Y2_OFF  = 50331648;                // + 50331648
constexpr size_t A0P_OFF = 100663296;               // 16384*1024*2 = 33554432
constexpr size_t A1P_OFF = 134217728;               // + 33554432
constexpr size_t A20_OFF = 167772160;               // 16384*256*2  = 8388608
constexpr size_t A21_OFF = 176160768;               // ends 184549376 < 268435456

// ---------------- d_ws layout (bytes) ----------------
constexpr size_t MASK_OFF = 0;            // 16384*4
constexpr size_t B10_OFF  = 65536;        // 786432*2 = 1572864
constexpr size_t B11_OFF  = 1638400;
constexpr size_t B20_OFF  = 3211264;      // 196608*2 = 393216
constexpr size_t B21_OFF  = 3604480;
constexpr size_t DUR_OFF  = 3997696;      // 16384*4
constexpr size_t CUM_OFF  = 4063232;      // 16384*4

__device__ __forceinline__ void split_f16(float x, half_t& hi, half_t& lo) {
    half_t h = (half_t)x;
    float r = x - (float)h;          // exact
    hi = h;
    lo = (half_t)(r * 4096.0f);      // lo part pre-scaled by 2^12 (avoids f16 denormals)
}

__device__ __forceinline__ void gload_lds16(const void* g, void* l) {
    __builtin_amdgcn_global_load_lds(
        (const __attribute__((address_space(1))) unsigned int*)g,
        (__attribute__((address_space(3))) unsigned int*)l, 16, 0, 0);
}

// ---------------- mask prep (dtype-robust; mask[0][1] is guaranteed true) ----------------
__global__ void prep_mask_kernel(const unsigned char* __restrict__ raw,
                                 float* __restrict__ maskf) {
    int i = blockIdx.x * 256 + threadIdx.x;
    if (i >= M_) return;
    bool bytefmt = (raw[1] == 1);
    float v;
    if (bytefmt) v = (raw[i] != 0) ? 1.0f : 0.0f;
    else {
        const int* wi = reinterpret_cast<const int*>(raw);
        v = (wi[i] != 0) ? 1.0f : 0.0f;
    }
    maskf[i] = v;
}

// ---------------- A split+block: seqs*mask -> A0p/A1p [bm][bk=32][64][8] f16 ----------------
__global__ __launch_bounds__(256) void split_A_kernel(
    const float* __restrict__ X, const float* __restrict__ mask,
    half_t* __restrict__ A0p, half_t* __restrict__ A1p) {
    const int bm = blockIdx.x;              // 0..1023 (row-block of 16)
    const int l = threadIdx.x & 63;
    const int bk4 = threadIdx.x >> 6;       // 0..3
    const int row = bm * 16 + (l & 15);
    const float mv = mask[row];
    const float* src = X + (size_t)row * E_ + ((l >> 4) * 8);
#pragma unroll
    for (int g = 0; g < 8; ++g) {
        const int bk = g * 4 + bk4;         // 0..31
        float4 v0 = *reinterpret_cast<const float4*>(src + bk * 32);
        float4 v1 = *reinterpret_cast<const float4*>(src + bk * 32 + 4);
        float v[8] = {v0.x, v0.y, v0.z, v0.w, v1.x, v1.y, v1.z, v1.w};
        f16x8 h8, l8;
#pragma unroll
        for (int j = 0; j < 8; ++j) {
            half_t hi, lo; split_f16(v[j] * mv, hi, lo);
            h8[j] = hi; l8[j] = lo;
        }
        size_t co = ((size_t)(bm * 32 + bk) * 64 + l) * 8;
        *reinterpret_cast<f16x8*>(A0p + co) = h8;
        *reinterpret_cast<f16x8*>(A1p + co) = l8;
    }
}

// ---------------- W split+block: w[h][e][k] -> B[e][j=k*256+h] blocked [bk][bj=48][64][8] ----------------
template <int EIN>   // EIN=1024 (conv1) or 256 (conv2); NBK=EIN/32
__global__ void split_W_kernel(const float* __restrict__ w,
                               half_t* __restrict__ B0p, half_t* __restrict__ B1p) {
    const int c = blockIdx.x * 256 + threadIdx.x;   // chunk id over NBK*48*64
    const int l = c & 63;
    const int t = c >> 6;
    const int bj = t % NJ16;
    const int bk = t / NJ16;
    const int j = bj * 16 + (l & 15);
    const int k = j >> 8;           // 0..2
    const int h = j & 255;
    const int e0 = bk * 32 + ((l >> 4) * 8);
    f16x8 h8, l8;
#pragma unroll
    for (int jj = 0; jj < 8; ++jj) {
        float x = w[((size_t)h * EIN + e0 + jj) * 3 + k];
        half_t hi, lo; split_f16(x, hi, lo);
        h8[jj] = hi; l8[jj] = lo;
    }
    size_t co = (size_t)c * 8;
    *reinterpret_cast<f16x8*>(B0p + co) = h8;
    *reinterpret_cast<f16x8*>(B1p + co) = l8;
}

// ---------------- split-f16 3-pass MFMA GEMM: Y[M][768] = A[M][K] * B[K][768] ----------------
template <int NBK>   // K = NBK*32; conv1: 32, conv2: 8
__global__ __launch_bounds__(256, 2) void gemm_split_kernel(
    const half_t* __restrict__ A0p, const half_t* __restrict__ A1p,
    const half_t* __restrict__ B0p, const half_t* __restrict__ B1p,
    float* __restrict__ Y) {
    __shared__ __align__(16) half_t lds[4][4096];   // A0,A1,B0,B1 tiles: 8KB each
    const int tid = threadIdx.x;
    const int l = tid & 63;
    const int wv = tid >> 6;
    const int wr = wv >> 1, wc = wv & 1;
    const int bm0 = blockIdx.x * 8;     // m-block base (rows of 16)
    const int bj0 = blockIdx.y * 8;     // j-block base (cols of 16)

    f32x4 acch[4][4] = {};
    f32x4 accl[4][4] = {};

    for (int kb = 0; kb < NBK; ++kb) {
#pragma unroll
        for (int s = 0; s < 2; ++s) {
            const int q = tid + 256 * s;          // 0..511 chunk in tile
            const int blk = q >> 6;
            const int ql = q & 63;
            const size_t aoff = (((size_t)(bm0 + blk) * NBK + kb) * 64 + ql) * 8;
            const size_t boff = (((size_t)kb * NJ16 + bj0 + blk) * 64 + ql) * 8;
            gload_lds16(A0p + aoff, &lds[0][(size_t)q * 8]);
            gload_lds16(A1p + aoff, &lds[1][(size_t)q * 8]);
            gload_lds16(B0p + boff, &lds[2][(size_t)q * 8]);
            gload_lds16(B1p + boff, &lds[3][(size_t)q * 8]);
        }
        __syncthreads();

        f16x8 b0f[4], b1f[4];
#pragma unroll
        for (int nb = 0; nb < 4; ++nb) {
            const int idx = ((wc * 4 + nb) * 64 + l) * 8;
            b0f[nb] = *reinterpret_cast<const f16x8*>(&lds[2][idx]);
            b1f[nb] = *reinterpret_cast<const f16x8*>(&lds[3][idx]);
        }
#pragma unroll
        for (int mb = 0; mb < 4; ++mb) {
            const int idx = ((wr * 4 + mb) * 64 + l) * 8;
            f16x8 a0 = *reinterpret_cast<const f16x8*>(&lds[0][idx]);
            f16x8 a1 = *reinterpret_cast<const f16x8*>(&lds[1][idx]);
#pragma unroll
            for (int nb = 0; nb < 4; ++nb) {
                acch[mb][nb] = __builtin_amdgcn_mfma_f32_16x16x32_f16(a0, b0f[nb], acch[mb][nb], 0, 0, 0);
                accl[mb][nb] = __builtin_amdgcn_mfma_f32_16x16x32_f16(a0, b1f[nb], accl[mb][nb], 0, 0, 0);
                accl[mb][nb] = __builtin_amdgcn_mfma_f32_16x16x32_f16(a1, b0f[nb], accl[mb][nb], 0, 0, 0);
            }
        }
        __syncthreads();
    }

    const int mrow0 = blockIdx.x * 128 + wr * 64;
    const int jcol0 = blockIdx.y * 128 + wc * 64;
#pragma unroll
    for (int mb = 0; mb < 4; ++mb)
#pragma unroll
        for (int nb = 0; nb < 4; ++nb) {
            const int j = jcol0 + nb * 16 + (l & 15);
            const int mbase = mrow0 + mb * 16 + (l >> 4) * 4;
#pragma unroll
            for (int r = 0; r < 4; ++r)
                Y[(size_t)(mbase + r) * NJ + j] = acch[mb][nb][r] + accl[mb][nb][r] * 0x1p-12f;
        }
}

// ---------------- combine(3-tap) + bias + relu + LN + *mask -> split-blocked A2 ----------------
__global__ __launch_bounds__(256) void ln1_split_kernel(
    const float* __restrict__ Y1, const float* __restrict__ cb,
    const float* __restrict__ g, const float* __restrict__ b,
    const float* __restrict__ mask,
    half_t* __restrict__ A20, half_t* __restrict__ A21) {
    __shared__ float xs[16][260];
    __shared__ float shs[4], shss[4];
    const int h = threadIdx.x;
    const int bm = blockIdx.x;
    const int wid = h >> 6, lane = h & 63;
    for (int r = 0; r < 16; ++r) {
        const int t = bm * 16 + r;
        float v = Y1[(size_t)t * NJ + 256 + h] + cb[h];
        if ((t & (T_ - 1)) != 0)      v += Y1[(size_t)(t - 1) * NJ + h];
        if ((t & (T_ - 1)) != T_ - 1) v += Y1[(size_t)(t + 1) * NJ + 512 + h];
        v = fmaxf(v, 0.0f);
        float s = v, ss = v * v;
#pragma unroll
        for (int off = 32; off; off >>= 1) {
            s  += __shfl_down(s, off);
            ss += __shfl_down(ss, off);
        }
        if (lane == 0) { shs[wid] = s; shss[wid] = ss; }
        __syncthreads();
        const float S  = shs[0] + shs[1] + shs[2] + shs[3];
        const float SS = shss[0] + shss[1] + shss[2] + shss[3];
        const float mu  = S * (1.0f / H_);
        const float var = SS * (1.0f / H_) - mu * mu;
        const float inv = 1.0f / sqrtf(var + 1e-5f);
        xs[r][h] = ((v - mu) * inv * g[h] + b[h]) * mask[t];
        __syncthreads();
    }
#pragma unroll
    for (int s2 = 0; s2 < 2; ++s2) {
        const int q = threadIdx.x + 256 * s2;   // 0..511
        const int l = q & 63;
        const int bk = q >> 6;                  // 0..7
        const int rr = l & 15;
        const int h0 = bk * 32 + ((l >> 4) * 8);
        f16x8 h8, l8;
#pragma unroll
        for (int jj = 0; jj < 8; ++jj) {
            half_t hi, lo; split_f16(xs[rr][h0 + jj], hi, lo);
            h8[jj] = hi; l8[jj] = lo;
        }
        size_t co = ((size_t)(bm * 8 + bk) * 64 + l) * 8;
        *reinterpret_cast<f16x8*>(A20 + co) = h8;
        *reinterpret_cast<f16x8*>(A21 + co) = l8;
    }
}

// ---------------- combine + bias + relu + LN + proj + duration ----------------
__global__ __launch_bounds__(256) void ln2_proj_dur_kernel(
    const float* __restrict__ Y2, const float* __restrict__ cb,
    const float* __restrict__ g, const float* __restrict__ b,
    const float* __restrict__ pw, const float* __restrict__ pb,
    const float* __restrict__ mask, int* __restrict__ dur) {
    const int t = blockIdx.x;
    const int h = threadIdx.x;
    const int wid = h >> 6, lane = h & 63;
    float v = Y2[(size_t)t * NJ + 256 + h] + cb[h];
    if ((t & (T_ - 1)) != 0)      v += Y2[(size_t)(t - 1) * NJ + h];
    if ((t & (T_ - 1)) != T_ - 1) v += Y2[(size_t)(t + 1) * NJ + 512 + h];
    v = fmaxf(v, 0.0f);
    float s = v, ss = v * v;
#pragma unroll
    for (int off = 32; off; off >>= 1) {
        s  += __shfl_down(s, off);
        ss += __shfl_down(ss, off);
    }
    __shared__ float shs[4], shss[4], shc[4];
    if (lane == 0) { shs[wid] = s; shss[wid] = ss; }
    __syncthreads();
    const float S  = shs[0] + shs[1] + shs[2] + shs[3];
    const float SS = shss[0] + shss[1] + shss[2] + shss[3];
    const float mu  = S * (1.0f / H_);
    const float var = SS * (1.0f / H_) - mu * mu;
    const float inv = 1.0f / sqrtf(var + 1e-5f);
    const float y = (v - mu) * inv * g[h] + b[h];
    float c = y * pw[h];
#pragma unroll
    for (int off = 32; off; off >>= 1) c += __shfl_down(c, off);
    if (lane == 0) shc[wid] = c;
    __syncthreads();
    if (h == 0) {
        const float ld = shc[0] + shc[1] + shc[2] + shc[3] + pb[0];
        const float dv = rintf(expf(ld) - 1.0f);
        int di = (int)dv;
        if (di < 0) di = 0;
        if (mask[t] == 0.0f) di = 0;
        dur[t] = di;
    }
}

// ---------------- per-sequence inclusive cumsum (T=1024) ----------------
__global__ __launch_bounds__(1024) void cumsum_kernel(
    const int* __restrict__ dur, int* __restrict__ cum,
    float* __restrict__ seq_lens_out) {
    __shared__ int s[1024];
    const int n = blockIdx.x, t = threadIdx.x;
    s[t] = dur[n * T_ + t];
    __syncthreads();
    for (int off = 1; off < 1024; off <<= 1) {
        int v = (t >= off) ? s[t - off] : 0;
        __syncthreads();
        s[t] += v;
        __syncthreads();
    }
    cum[n * T_ + t] = s[t];
    if (t == T_ - 1) seq_lens_out[n] = (float)s[t];
}

// ---------------- length-regulator upsample ----------------
__global__ __launch_bounds__(256) void upsample_kernel(
    const float* __restrict__ seqs, const int* __restrict__ cum,
    float* __restrict__ out) {
    const int bp = blockIdx.x;           // n*MAXOUT + p
    const int n = bp >> 12;
    const int p = bp & (MAXOUT - 1);
    __shared__ int sh_idx, sh_valid;
    if (threadIdx.x == 0) {
        const int* c = cum + n * T_;
        const int slen = c[T_ - 1];
        int lo = 0, hi = T_;
        while (lo < hi) {
            int mid = (lo + hi) >> 1;
            if (c[mid] <= p) lo = mid + 1; else hi = mid;
        }
        sh_idx = (lo < T_ - 1) ? lo : (T_ - 1);
        sh_valid = (p < slen) ? 1 : 0;
    }
    __syncthreads();
    float4 v = make_float4(0.f, 0.f, 0.f, 0.f);
    if (sh_valid) {
        const float4* src = reinterpret_cast<const float4*>(
            seqs + ((size_t)(n * T_ + sh_idx) * E_));
        v = src[threadIdx.x];
    }
    reinterpret_cast<float4*>(out + (size_t)bp * E_)[threadIdx.x] = v;
}

// ---------------- launch ----------------
extern "C" void kernel_launch(void* const* d_in, const int* in_sizes, int n_in,
                              void* d_out, int out_size, void* d_ws, size_t ws_size,
                              hipStream_t stream) {
    const float* seqs = (const float*)d_in[0];
    const float* w1   = (const float*)d_in[1];
    const float* b1   = (const float*)d_in[2];
    const float* g1   = (const float*)d_in[3];
    const float* bb1  = (const float*)d_in[4];
    const float* w2   = (const float*)d_in[5];
    const float* b2   = (const float*)d_in[6];
    const float* g2   = (const float*)d_in[7];
    const float* bb2  = (const float*)d_in[8];
    const float* pw   = (const float*)d_in[9];
    const float* pb   = (const float*)d_in[10];
    const unsigned char* mraw = (const unsigned char*)d_in[11];

    char* wsb = (char*)d_ws;
    float* maskf = (float*)(wsb + MASK_OFF);
    half_t* B10  = (half_t*)(wsb + B10_OFF);
    half_t* B11  = (half_t*)(wsb + B11_OFF);
    half_t* B20  = (half_t*)(wsb + B20_OFF);
    half_t* B21  = (half_t*)(wsb + B21_OFF);
    int* dur = (int*)(wsb + DUR_OFF);
    int* cum = (int*)(wsb + CUM_OFF);

    char* outb = (char*)d_out;
    float* Y1   = (float*)(outb + Y1_OFF);
    float* Y2   = (float*)(outb + Y2_OFF);
    half_t* A0p = (half_t*)(outb + A0P_OFF);
    half_t* A1p = (half_t*)(outb + A1P_OFF);
    half_t* A20 = (half_t*)(outb + A20_OFF);
    half_t* A21 = (half_t*)(outb + A21_OFF);

    float* out      = (float*)d_out;
    float* slen_out = out + (size_t)N_ * MAXOUT * E_;

    prep_mask_kernel<<<M_ / 256, 256, 0, stream>>>(mraw, maskf);
    split_A_kernel<<<M_ / 16, 256, 0, stream>>>(seqs, maskf, A0p, A1p);
    split_W_kernel<E_><<<(32 * NJ16 * 64) / 256, 256, 0, stream>>>(w1, B10, B11);
    split_W_kernel<H_><<<(8 * NJ16 * 64) / 256, 256, 0, stream>>>(w2, B20, B21);

    gemm_split_kernel<32><<<dim3(M_ / 128, NJ / 128), 256, 0, stream>>>(A0p, A1p, B10, B11, Y1);
    ln1_split_kernel<<<M_ / 16, 256, 0, stream>>>(Y1, b1, g1, bb1, maskf, A20, A21);
    gemm_split_kernel<8><<<dim3(M_ / 128, NJ / 128), 256, 0, stream>>>(A20, A21, B20, B21, Y2);
    ln2_proj_dur_kernel<<<M_, 256, 0, stream>>>(Y2, b2, g2, bb2, pw, pb, maskf, dur);
    cumsum_kernel<<<N_, 1024, 0, stream>>>(dur, cum, slen_out);
    upsample_kernel<<<N_ * MAXOUT, 256, 0, stream>>>(seqs, cum, out);
}

// Round 3
// 246.195 us; speedup vs baseline: 2.6063x; 1.0998x over previous
//
#include <hip/hip_runtime.h>

#define N_ 16
#define T_ 1024
#define E_ 1024
#define H_ 256
#define MAXOUT 4096
#define M_ (N_ * T_)          // 16384 rows
#define NJ 768                // 3*H_ GEMM output cols
#define NJ16 48               // NJ/16

typedef _Float16 half_t;
typedef __attribute__((ext_vector_type(8))) _Float16 f16x8;
typedef __attribute__((ext_vector_type(4))) float f32x4;

// ---------------- d_out scratch layout (bytes) ----------------
// upsample (last kernel) rewrites the entire main output region.
constexpr size_t Y1_OFF  = 0;                       // 16384*768*4  = 50331648
constexpr size_t Y2_OFF  = 50331648;                // + 50331648
constexpr size_t A0P_OFF = 100663296;               // 16384*1024*2 = 33554432
constexpr size_t A1P_OFF = 134217728;               // + 33554432
constexpr size_t A20_OFF = 167772160;               // 16384*256*2  = 8388608
constexpr size_t A21_OFF = 176160768;               // ends 184549376 < 268435456

// ---------------- d_ws layout (bytes) ----------------
constexpr size_t B10_OFF  = 0;            // 786432*2 = 1572864
constexpr size_t B11_OFF  = 1572864;
constexpr size_t B20_OFF  = 3145728;      // 196608*2 = 393216
constexpr size_t B21_OFF  = 3538944;
constexpr size_t DUR_OFF  = 3932160;      // 16384*4
constexpr size_t CUM_OFF  = 3997696;      // 16384*4

__device__ __forceinline__ void split_f16(float x, half_t& hi, half_t& lo) {
    half_t h = (half_t)x;
    float r = x - (float)h;          // exact
    hi = h;
    lo = (half_t)(r * 4096.0f);      // lo part pre-scaled by 2^12 (avoids f16 denormals)
}

// mask decode, dtype-robust. padding_mask[0][1] is guaranteed true (lens>=512):
// bool-byte storage -> raw[1]==1; int32/float32 -> raw[1]==0, read 4-byte words.
__device__ __forceinline__ float mask_at(const unsigned char* __restrict__ raw, int i) {
    if (raw[1] == 1) return raw[i] ? 1.0f : 0.0f;
    return reinterpret_cast<const int*>(raw)[i] ? 1.0f : 0.0f;
}

__device__ __forceinline__ void gload_lds16(const void* g, void* l) {
    __builtin_amdgcn_global_load_lds(
        (const __attribute__((address_space(1))) unsigned int*)g,
        (__attribute__((address_space(3))) unsigned int*)l, 16, 0, 0);
}

// ---------------- fused prep: split_A (blocks 0..1023) | split W1 (..1407) | split W2 (..1503) ----
// A: seqs*mask -> A0p/A1p  [bm][bk=32][64][8] f16 fragment-blocked
// W: w[h][e][k] -> B[e][j=k*256+h] blocked [bk][bj=48][64][8]
__global__ __launch_bounds__(256) void prep_all_kernel(
    const float* __restrict__ X, const unsigned char* __restrict__ mraw,
    const float* __restrict__ w1, const float* __restrict__ w2,
    half_t* __restrict__ A0p, half_t* __restrict__ A1p,
    half_t* __restrict__ B10, half_t* __restrict__ B11,
    half_t* __restrict__ B20, half_t* __restrict__ B21) {
    const int bid = blockIdx.x;
    if (bid < 1024) {
        // ---- split A ----
        const int bm = bid;
        const int l = threadIdx.x & 63;
        const int bk4 = threadIdx.x >> 6;       // 0..3
        const int row = bm * 16 + (l & 15);
        const float mv = mask_at(mraw, row);
        const float* src = X + (size_t)row * E_ + ((l >> 4) * 8);
#pragma unroll
        for (int g = 0; g < 8; ++g) {
            const int bk = g * 4 + bk4;         // 0..31
            float4 v0 = *reinterpret_cast<const float4*>(src + bk * 32);
            float4 v1 = *reinterpret_cast<const float4*>(src + bk * 32 + 4);
            float v[8] = {v0.x, v0.y, v0.z, v0.w, v1.x, v1.y, v1.z, v1.w};
            f16x8 h8, l8;
#pragma unroll
            for (int j = 0; j < 8; ++j) {
                half_t hi, lo; split_f16(v[j] * mv, hi, lo);
                h8[j] = hi; l8[j] = lo;
            }
            size_t co = ((size_t)(bm * 32 + bk) * 64 + l) * 8;
            *reinterpret_cast<f16x8*>(A0p + co) = h8;
            *reinterpret_cast<f16x8*>(A1p + co) = l8;
        }
    } else {
        const bool isW1 = (bid < 1024 + 384);
        const int c = (isW1 ? (bid - 1024) : (bid - 1408)) * 256 + threadIdx.x;
        const int EIN = isW1 ? E_ : H_;
        const float* w = isW1 ? w1 : w2;
        half_t* B0p = isW1 ? B10 : B20;
        half_t* B1p = isW1 ? B11 : B21;
        const int l = c & 63;
        const int t = c >> 6;
        const int bj = t % NJ16;
        const int bk = t / NJ16;
        const int j = bj * 16 + (l & 15);
        const int k = j >> 8;           // 0..2
        const int h = j & 255;
        const int e0 = bk * 32 + ((l >> 4) * 8);
        f16x8 h8, l8;
#pragma unroll
        for (int jj = 0; jj < 8; ++jj) {
            float x = w[((size_t)h * EIN + e0 + jj) * 3 + k];
            half_t hi, lo; split_f16(x, hi, lo);
            h8[jj] = hi; l8[jj] = lo;
        }
        size_t co = (size_t)c * 8;
        *reinterpret_cast<f16x8*>(B0p + co) = h8;
        *reinterpret_cast<f16x8*>(B1p + co) = l8;
    }
}

// ---------------- split-f16 3-pass MFMA GEMM, 2-phase double-buffered ----------------
// Y[M][768] = A[M][K] * B[K][768];  K = NBK*32
template <int NBK>   // conv1: 32, conv2: 8
__global__ __launch_bounds__(256, 2) void gemm_split_kernel(
    const half_t* __restrict__ A0p, const half_t* __restrict__ A1p,
    const half_t* __restrict__ B0p, const half_t* __restrict__ B1p,
    float* __restrict__ Y) {
    __shared__ __align__(16) half_t lds[2][4][4096];   // [buf][A0,A1,B0,B1][128x32 tile]
    const int tid = threadIdx.x;
    const int l = tid & 63;
    const int wv = tid >> 6;
    const int wr = wv >> 1, wc = wv & 1;
    const int bm0 = blockIdx.x * 8;     // m-block base (rows of 16)
    const int bj0 = blockIdx.y * 8;     // j-block base (cols of 16)

    f32x4 acch[4][4] = {};
    f32x4 accl[4][4] = {};

    auto stage = [&](int kb, int buf) {
#pragma unroll
        for (int s = 0; s < 2; ++s) {
            const int q = tid + 256 * s;          // 0..511 chunk in tile
            const int blk = q >> 6;
            const int ql = q & 63;
            const size_t aoff = (((size_t)(bm0 + blk) * NBK + kb) * 64 + ql) * 8;
            const size_t boff = (((size_t)kb * NJ16 + bj0 + blk) * 64 + ql) * 8;
            gload_lds16(A0p + aoff, &lds[buf][0][(size_t)q * 8]);
            gload_lds16(A1p + aoff, &lds[buf][1][(size_t)q * 8]);
            gload_lds16(B0p + boff, &lds[buf][2][(size_t)q * 8]);
            gload_lds16(B1p + boff, &lds[buf][3][(size_t)q * 8]);
        }
    };

    stage(0, 0);
    int cur = 0;
    for (int kb = 0; kb < NBK; ++kb) {
        __syncthreads();   // drains stage(kb) (vmcnt) + prior-tile reads (lgkm)

        // ds_read B fragments of current tile
        f16x8 b0f[4], b1f[4];
#pragma unroll
        for (int nb = 0; nb < 4; ++nb) {
            const int idx = ((wc * 4 + nb) * 64 + l) * 8;
            b0f[nb] = *reinterpret_cast<const f16x8*>(&lds[cur][2][idx]);
            b1f[nb] = *reinterpret_cast<const f16x8*>(&lds[cur][3][idx]);
        }
        // issue next-tile prefetch while computing this one
        if (kb + 1 < NBK) stage(kb + 1, cur ^ 1);

        __builtin_amdgcn_s_setprio(1);
#pragma unroll
        for (int mb = 0; mb < 4; ++mb) {
            const int idx = ((wr * 4 + mb) * 64 + l) * 8;
            f16x8 a0 = *reinterpret_cast<const f16x8*>(&lds[cur][0][idx]);
            f16x8 a1 = *reinterpret_cast<const f16x8*>(&lds[cur][1][idx]);
#pragma unroll
            for (int nb = 0; nb < 4; ++nb) {
                acch[mb][nb] = __builtin_amdgcn_mfma_f32_16x16x32_f16(a0, b0f[nb], acch[mb][nb], 0, 0, 0);
                accl[mb][nb] = __builtin_amdgcn_mfma_f32_16x16x32_f16(a0, b1f[nb], accl[mb][nb], 0, 0, 0);
                accl[mb][nb] = __builtin_amdgcn_mfma_f32_16x16x32_f16(a1, b0f[nb], accl[mb][nb], 0, 0, 0);
            }
        }
        __builtin_amdgcn_s_setprio(0);
        cur ^= 1;
    }

    const int mrow0 = blockIdx.x * 128 + wr * 64;
    const int jcol0 = blockIdx.y * 128 + wc * 64;
#pragma unroll
    for (int mb = 0; mb < 4; ++mb)
#pragma unroll
        for (int nb = 0; nb < 4; ++nb) {
            const int j = jcol0 + nb * 16 + (l & 15);
            const int mbase = mrow0 + mb * 16 + (l >> 4) * 4;
#pragma unroll
            for (int r = 0; r < 4; ++r)
                Y[(size_t)(mbase + r) * NJ + j] = acch[mb][nb][r] + accl[mb][nb][r] * 0x1p-12f;
        }
}

// ---------------- combine(3-tap) + bias + relu + LN + *mask -> split-blocked A2 ----------------
__global__ __launch_bounds__(256) void ln1_split_kernel(
    const float* __restrict__ Y1, const float* __restrict__ cb,
    const float* __restrict__ g, const float* __restrict__ b,
    const unsigned char* __restrict__ mraw,
    half_t* __restrict__ A20, half_t* __restrict__ A21) {
    __shared__ float xs[16][260];
    __shared__ float shs[4], shss[4];
    const int h = threadIdx.x;
    const int bm = blockIdx.x;
    const int wid = h >> 6, lane = h & 63;
    for (int r = 0; r < 16; ++r) {
        const int t = bm * 16 + r;
        float v = Y1[(size_t)t * NJ + 256 + h] + cb[h];
        if ((t & (T_ - 1)) != 0)      v += Y1[(size_t)(t - 1) * NJ + h];
        if ((t & (T_ - 1)) != T_ - 1) v += Y1[(size_t)(t + 1) * NJ + 512 + h];
        v = fmaxf(v, 0.0f);
        float s = v, ss = v * v;
#pragma unroll
        for (int off = 32; off; off >>= 1) {
            s  += __shfl_down(s, off);
            ss += __shfl_down(ss, off);
        }
        if (lane == 0) { shs[wid] = s; shss[wid] = ss; }
        __syncthreads();
        const float S  = shs[0] + shs[1] + shs[2] + shs[3];
        const float SS = shss[0] + shss[1] + shss[2] + shss[3];
        const float mu  = S * (1.0f / H_);
        const float var = SS * (1.0f / H_) - mu * mu;
        const float inv = 1.0f / sqrtf(var + 1e-5f);
        xs[r][h] = ((v - mu) * inv * g[h] + b[h]) * mask_at(mraw, t);
        __syncthreads();
    }
#pragma unroll
    for (int s2 = 0; s2 < 2; ++s2) {
        const int q = threadIdx.x + 256 * s2;   // 0..511
        const int l = q & 63;
        const int bk = q >> 6;                  // 0..7
        const int rr = l & 15;
        const int h0 = bk * 32 + ((l >> 4) * 8);
        f16x8 h8, l8;
#pragma unroll
        for (int jj = 0; jj < 8; ++jj) {
            half_t hi, lo; split_f16(xs[rr][h0 + jj], hi, lo);
            h8[jj] = hi; l8[jj] = lo;
        }
        size_t co = ((size_t)(bm * 8 + bk) * 64 + l) * 8;
        *reinterpret_cast<f16x8*>(A20 + co) = h8;
        *reinterpret_cast<f16x8*>(A21 + co) = l8;
    }
}

// ---------------- combine + bias + relu + LN + proj + duration ----------------
__global__ __launch_bounds__(256) void ln2_proj_dur_kernel(
    const float* __restrict__ Y2, const float* __restrict__ cb,
    const float* __restrict__ g, const float* __restrict__ b,
    const float* __restrict__ pw, const float* __restrict__ pb,
    const unsigned char* __restrict__ mraw, int* __restrict__ dur) {
    const int t = blockIdx.x;
    const int h = threadIdx.x;
    const int wid = h >> 6, lane = h & 63;
    float v = Y2[(size_t)t * NJ + 256 + h] + cb[h];
    if ((t & (T_ - 1)) != 0)      v += Y2[(size_t)(t - 1) * NJ + h];
    if ((t & (T_ - 1)) != T_ - 1) v += Y2[(size_t)(t + 1) * NJ + 512 + h];
    v = fmaxf(v, 0.0f);
    float s = v, ss = v * v;
#pragma unroll
    for (int off = 32; off; off >>= 1) {
        s  += __shfl_down(s, off);
        ss += __shfl_down(ss, off);
    }
    __shared__ float shs[4], shss[4], shc[4];
    if (lane == 0) { shs[wid] = s; shss[wid] = ss; }
    __syncthreads();
    const float S  = shs[0] + shs[1] + shs[2] + shs[3];
    const float SS = shss[0] + shss[1] + shss[2] + shss[3];
    const float mu  = S * (1.0f / H_);
    const float var = SS * (1.0f / H_) - mu * mu;
    const float inv = 1.0f / sqrtf(var + 1e-5f);
    const float y = (v - mu) * inv * g[h] + b[h];
    float c = y * pw[h];
#pragma unroll
    for (int off = 32; off; off >>= 1) c += __shfl_down(c, off);
    if (lane == 0) shc[wid] = c;
    __syncthreads();
    if (h == 0) {
        const float ld = shc[0] + shc[1] + shc[2] + shc[3] + pb[0];
        const float dv = rintf(expf(ld) - 1.0f);
        int di = (int)dv;
        if (di < 0) di = 0;
        if (mask_at(mraw, t) == 0.0f) di = 0;
        dur[t] = di;
    }
}

// ---------------- per-sequence inclusive cumsum (T=1024) ----------------
__global__ __launch_bounds__(1024) void cumsum_kernel(
    const int* __restrict__ dur, int* __restrict__ cum,
    float* __restrict__ seq_lens_out) {
    __shared__ int s[1024];
    const int n = blockIdx.x, t = threadIdx.x;
    s[t] = dur[n * T_ + t];
    __syncthreads();
    for (int off = 1; off < 1024; off <<= 1) {
        int v = (t >= off) ? s[t - off] : 0;
        __syncthreads();
        s[t] += v;
        __syncthreads();
    }
    cum[n * T_ + t] = s[t];
    if (t == T_ - 1) seq_lens_out[n] = (float)s[t];
}

// ---------------- length-regulator upsample ----------------
__global__ __launch_bounds__(256) void upsample_kernel(
    const float* __restrict__ seqs, const int* __restrict__ cum,
    float* __restrict__ out) {
    const int bp = blockIdx.x;           // n*MAXOUT + p
    const int n = bp >> 12;
    const int p = bp & (MAXOUT - 1);
    __shared__ int sh_idx, sh_valid;
    if (threadIdx.x == 0) {
        const int* c = cum + n * T_;
        const int slen = c[T_ - 1];
        int lo = 0, hi = T_;
        while (lo < hi) {
            int mid = (lo + hi) >> 1;
            if (c[mid] <= p) lo = mid + 1; else hi = mid;
        }
        sh_idx = (lo < T_ - 1) ? lo : (T_ - 1);
        sh_valid = (p < slen) ? 1 : 0;
    }
    __syncthreads();
    float4 v = make_float4(0.f, 0.f, 0.f, 0.f);
    if (sh_valid) {
        const float4* src = reinterpret_cast<const float4*>(
            seqs + ((size_t)(n * T_ + sh_idx) * E_));
        v = src[threadIdx.x];
    }
    reinterpret_cast<float4*>(out + (size_t)bp * E_)[threadIdx.x] = v;
}

// ---------------- launch ----------------
extern "C" void kernel_launch(void* const* d_in, const int* in_sizes, int n_in,
                              void* d_out, int out_size, void* d_ws, size_t ws_size,
                              hipStream_t stream) {
    const float* seqs = (const float*)d_in[0];
    const float* w1   = (const float*)d_in[1];
    const float* b1   = (const float*)d_in[2];
    const float* g1   = (const float*)d_in[3];
    const float* bb1  = (const float*)d_in[4];
    const float* w2   = (const float*)d_in[5];
    const float* b2   = (const float*)d_in[6];
    const float* g2   = (const float*)d_in[7];
    const float* bb2  = (const float*)d_in[8];
    const float* pw   = (const float*)d_in[9];
    const float* pb   = (const float*)d_in[10];
    const unsigned char* mraw = (const unsigned char*)d_in[11];

    char* wsb = (char*)d_ws;
    half_t* B10  = (half_t*)(wsb + B10_OFF);
    half_t* B11  = (half_t*)(wsb + B11_OFF);
    half_t* B20  = (half_t*)(wsb + B20_OFF);
    half_t* B21  = (half_t*)(wsb + B21_OFF);
    int* dur = (int*)(wsb + DUR_OFF);
    int* cum = (int*)(wsb + CUM_OFF);

    char* outb = (char*)d_out;
    float* Y1   = (float*)(outb + Y1_OFF);
    float* Y2   = (float*)(outb + Y2_OFF);
    half_t* A0p = (half_t*)(outb + A0P_OFF);
    half_t* A1p = (half_t*)(outb + A1P_OFF);
    half_t* A20 = (half_t*)(outb + A20_OFF);
    half_t* A21 = (half_t*)(outb + A21_OFF);

    float* out      = (float*)d_out;
    float* slen_out = out + (size_t)N_ * MAXOUT * E_;

    // fused: split_A (1024 blocks) | split W1 (384) | split W2 (96)
    prep_all_kernel<<<1504, 256, 0, stream>>>(seqs, mraw, w1, w2,
                                              A0p, A1p, B10, B11, B20, B21);
    gemm_split_kernel<32><<<dim3(M_ / 128, NJ / 128), 256, 0, stream>>>(A0p, A1p, B10, B11, Y1);
    ln1_split_kernel<<<M_ / 16, 256, 0, stream>>>(Y1, b1, g1, bb1, mraw, A20, A21);
    gemm_split_kernel<8><<<dim3(M_ / 128, NJ / 128), 256, 0, stream>>>(A20, A21, B20, B21, Y2);
    ln2_proj_dur_kernel<<<M_, 256, 0, stream>>>(Y2, b2, g2, bb2, pw, pb, mraw, dur);
    cumsum_kernel<<<N_, 1024, 0, stream>>>(dur, cum, slen_out);
    upsample_kernel<<<N_ * MAXOUT, 256, 0, stream>>>(seqs, cum, out);
}

// Round 4
// 152.089 us; speedup vs baseline: 4.2190x; 1.6188x over previous
//
#include <hip/hip_runtime.h>

#define N_ 16
#define T_ 1024
#define E_ 1024
#define H_ 256
#define MAXOUT 4096
#define M_ (N_ * T_)          // 16384 rows
#define NJ 768                // 3*H_ GEMM output cols
#define NJ16 48               // NJ/16

typedef _Float16 half_t;
typedef __attribute__((ext_vector_type(8))) _Float16 f16x8;
typedef __attribute__((ext_vector_type(4))) _Float16 f16x4;
typedef __attribute__((ext_vector_type(4))) float f32x4;

// ---------------- d_out scratch layout (bytes) ----------------
// upsample (last kernel) rewrites the entire main output region.
constexpr size_t Y1_OFF  = 0;                       // 16384*768*2  = 25165824
constexpr size_t Y2_OFF  = 25165824;                // + 25165824
constexpr size_t A0P_OFF = 50331648;                // 16384*1024*2 = 33554432
constexpr size_t A2P_OFF = 83886080;                // 16384*256*2  = 8388608 -> ends 92274688

// ---------------- d_ws layout (bytes) ----------------
constexpr size_t B1P_OFF  = 0;            // 786432*2 = 1572864
constexpr size_t B2P_OFF  = 1572864;      // 196608*2 = 393216
constexpr size_t DUR_OFF  = 1966080;      // 16384*4
constexpr size_t CUM_OFF  = 2031616;      // 16384*4

// mask decode, dtype-robust. padding_mask[0][1] is guaranteed true (lens>=512):
// bool-byte storage -> raw[1]==1; int32/float32 -> raw[1]==0, read 4-byte words.
__device__ __forceinline__ float mask_at(const unsigned char* __restrict__ raw, int i) {
    if (raw[1] == 1) return raw[i] ? 1.0f : 0.0f;
    return reinterpret_cast<const int*>(raw)[i] ? 1.0f : 0.0f;
}

__device__ __forceinline__ void gload_lds16(const void* g, void* l) {
    __builtin_amdgcn_global_load_lds(
        (const __attribute__((address_space(1))) unsigned int*)g,
        (__attribute__((address_space(3))) unsigned int*)l, 16, 0, 0);
}

// ---------------- fused prep: A-convert (blocks 0..1023) | W1 (..1407) | W2 (..1503) ----
// A: seqs*mask -> A0p [bm][bk=32][64][8] f16 fragment-blocked
// W: w[h][e][k] -> B[e][j=k*256+h] blocked [bk][bj=48][64][8] f16
__global__ __launch_bounds__(256) void prep_all_kernel(
    const float* __restrict__ X, const unsigned char* __restrict__ mraw,
    const float* __restrict__ w1, const float* __restrict__ w2,
    half_t* __restrict__ A0p, half_t* __restrict__ B1p, half_t* __restrict__ B2p) {
    const int bid = blockIdx.x;
    if (bid < 1024) {
        const int bm = bid;
        const int l = threadIdx.x & 63;
        const int bk4 = threadIdx.x >> 6;       // 0..3
        const int row = bm * 16 + (l & 15);
        const float mv = mask_at(mraw, row);
        const float* src = X + (size_t)row * E_ + ((l >> 4) * 8);
#pragma unroll
        for (int g = 0; g < 8; ++g) {
            const int bk = g * 4 + bk4;         // 0..31
            float4 v0 = *reinterpret_cast<const float4*>(src + bk * 32);
            float4 v1 = *reinterpret_cast<const float4*>(src + bk * 32 + 4);
            float v[8] = {v0.x, v0.y, v0.z, v0.w, v1.x, v1.y, v1.z, v1.w};
            f16x8 h8;
#pragma unroll
            for (int j = 0; j < 8; ++j) h8[j] = (half_t)(v[j] * mv);
            *reinterpret_cast<f16x8*>(A0p + ((size_t)(bm * 32 + bk) * 64 + l) * 8) = h8;
        }
    } else {
        const bool isW1 = (bid < 1024 + 384);
        const int c = (isW1 ? (bid - 1024) : (bid - 1408)) * 256 + threadIdx.x;
        const int EIN = isW1 ? E_ : H_;
        const float* w = isW1 ? w1 : w2;
        half_t* Bp = isW1 ? B1p : B2p;
        const int l = c & 63;
        const int t = c >> 6;
        const int bj = t % NJ16;
        const int bk = t / NJ16;
        const int j = bj * 16 + (l & 15);
        const int k = j >> 8;           // 0..2
        const int h = j & 255;
        const int e0 = bk * 32 + ((l >> 4) * 8);
        f16x8 h8;
#pragma unroll
        for (int jj = 0; jj < 8; ++jj)
            h8[jj] = (half_t)w[((size_t)h * EIN + e0 + jj) * 3 + k];
        *reinterpret_cast<f16x8*>(Bp + (size_t)c * 8) = h8;
    }
}

// ---------------- single-pass f16 MFMA GEMM, 2-phase dbuf, early prefetch ----------------
// Y[M][768] (f16) = A[M][K] * B[K][768];  K = NBK*32
template <int NBK>   // conv1: 32, conv2: 8
__global__ __launch_bounds__(256, 4) void gemm_f16_kernel(
    const half_t* __restrict__ Ap, const half_t* __restrict__ Bp,
    half_t* __restrict__ Y) {
    __shared__ __align__(16) half_t lds[2][2][4096];   // [buf][A,B][128x32 tile] = 32 KB
    const int tid = threadIdx.x;
    const int l = tid & 63;
    const int wv = tid >> 6;
    const int wr = wv >> 1, wc = wv & 1;
    const int bm0 = blockIdx.x * 8;     // m-block base (rows of 16)
    const int bj0 = blockIdx.y * 8;     // j-block base (cols of 16)

    f32x4 acc[4][4] = {};

    auto stage = [&](int kb, int buf) {
#pragma unroll
        for (int s = 0; s < 2; ++s) {
            const int q = tid + 256 * s;          // 0..511 chunk in tile
            const int blk = q >> 6;
            const int ql = q & 63;
            gload_lds16(Ap + (((size_t)(bm0 + blk) * NBK + kb) * 64 + ql) * 8,
                        &lds[buf][0][(size_t)q * 8]);
            gload_lds16(Bp + (((size_t)kb * NJ16 + bj0 + blk) * 64 + ql) * 8,
                        &lds[buf][1][(size_t)q * 8]);
        }
    };

    stage(0, 0);
    int cur = 0;
    for (int kb = 0; kb < NBK; ++kb) {
        __syncthreads();   // drains stage(kb) (vmcnt) + prior-tile reads (lgkm)
        // issue next-tile prefetch FIRST so ds_reads + MFMA cover its latency
        if (kb + 1 < NBK) stage(kb + 1, cur ^ 1);

        f16x8 bf[4];
#pragma unroll
        for (int nb = 0; nb < 4; ++nb)
            bf[nb] = *reinterpret_cast<const f16x8*>(&lds[cur][1][((wc * 4 + nb) * 64 + l) * 8]);

        __builtin_amdgcn_s_setprio(1);
#pragma unroll
        for (int mb = 0; mb < 4; ++mb) {
            f16x8 af = *reinterpret_cast<const f16x8*>(&lds[cur][0][((wr * 4 + mb) * 64 + l) * 8]);
#pragma unroll
            for (int nb = 0; nb < 4; ++nb)
                acc[mb][nb] = __builtin_amdgcn_mfma_f32_16x16x32_f16(af, bf[nb], acc[mb][nb], 0, 0, 0);
        }
        __builtin_amdgcn_s_setprio(0);
        cur ^= 1;
    }

    const int mrow0 = blockIdx.x * 128 + wr * 64;
    const int jcol0 = blockIdx.y * 128 + wc * 64;
#pragma unroll
    for (int mb = 0; mb < 4; ++mb)
#pragma unroll
        for (int nb = 0; nb < 4; ++nb) {
            const int j = jcol0 + nb * 16 + (l & 15);
            const int mbase = mrow0 + mb * 16 + (l >> 4) * 4;
#pragma unroll
            for (int r = 0; r < 4; ++r)
                Y[(size_t)(mbase + r) * NJ + j] = (half_t)acc[mb][nb][r];
        }
}

// ---------------- combine(3-tap) + bias + relu + LN + *mask -> fragment-blocked A2 (f16) ----
__global__ __launch_bounds__(256) void ln1_kernel(
    const half_t* __restrict__ Y1, const float* __restrict__ cb,
    const float* __restrict__ g, const float* __restrict__ b,
    const unsigned char* __restrict__ mraw,
    half_t* __restrict__ A2p) {
    __shared__ float xs[16][260];
    __shared__ float shs[4], shss[4];
    const int h = threadIdx.x;
    const int bm = blockIdx.x;
    const int wid = h >> 6, lane = h & 63;
    for (int r = 0; r < 16; ++r) {
        const int t = bm * 16 + r;
        float v = (float)Y1[(size_t)t * NJ + 256 + h] + cb[h];
        if ((t & (T_ - 1)) != 0)      v += (float)Y1[(size_t)(t - 1) * NJ + h];
        if ((t & (T_ - 1)) != T_ - 1) v += (float)Y1[(size_t)(t + 1) * NJ + 512 + h];
        v = fmaxf(v, 0.0f);
        float s = v, ss = v * v;
#pragma unroll
        for (int off = 32; off; off >>= 1) {
            s  += __shfl_down(s, off);
            ss += __shfl_down(ss, off);
        }
        if (lane == 0) { shs[wid] = s; shss[wid] = ss; }
        __syncthreads();
        const float S  = shs[0] + shs[1] + shs[2] + shs[3];
        const float SS = shss[0] + shss[1] + shss[2] + shss[3];
        const float mu  = S * (1.0f / H_);
        const float var = SS * (1.0f / H_) - mu * mu;
        const float inv = 1.0f / sqrtf(var + 1e-5f);
        xs[r][h] = ((v - mu) * inv * g[h] + b[h]) * mask_at(mraw, t);
        __syncthreads();
    }
#pragma unroll
    for (int s2 = 0; s2 < 2; ++s2) {
        const int q = threadIdx.x + 256 * s2;   // 0..511
        const int l = q & 63;
        const int bk = q >> 6;                  // 0..7
        const int rr = l & 15;
        const int h0 = bk * 32 + ((l >> 4) * 8);
        f16x8 h8;
#pragma unroll
        for (int jj = 0; jj < 8; ++jj) h8[jj] = (half_t)xs[rr][h0 + jj];
        *reinterpret_cast<f16x8*>(A2p + ((size_t)(bm * 8 + bk) * 64 + l) * 8) = h8;
    }
}

// ---------------- combine + bias + relu + LN + proj + duration (wave-per-row) ----------------
__global__ __launch_bounds__(256) void ln2_proj_dur_kernel(
    const half_t* __restrict__ Y2, const float* __restrict__ cb,
    const float* __restrict__ g, const float* __restrict__ b,
    const float* __restrict__ pw, const float* __restrict__ pb,
    const unsigned char* __restrict__ mraw, int* __restrict__ dur) {
    const int t = blockIdx.x * 4 + (threadIdx.x >> 6);
    const int lane = threadIdx.x & 63;
    const int h0 = lane * 4;

    f16x4 c4 = *reinterpret_cast<const f16x4*>(&Y2[(size_t)t * NJ + 256 + h0]);
    float v[4];
#pragma unroll
    for (int i = 0; i < 4; ++i) v[i] = (float)c4[i];
    if ((t & (T_ - 1)) != 0) {
        f16x4 l4 = *reinterpret_cast<const f16x4*>(&Y2[(size_t)(t - 1) * NJ + h0]);
#pragma unroll
        for (int i = 0; i < 4; ++i) v[i] += (float)l4[i];
    }
    if ((t & (T_ - 1)) != T_ - 1) {
        f16x4 r4 = *reinterpret_cast<const f16x4*>(&Y2[(size_t)(t + 1) * NJ + 512 + h0]);
#pragma unroll
        for (int i = 0; i < 4; ++i) v[i] += (float)r4[i];
    }
    float4 cb4 = *reinterpret_cast<const float4*>(&cb[h0]);
    v[0] = fmaxf(v[0] + cb4.x, 0.f); v[1] = fmaxf(v[1] + cb4.y, 0.f);
    v[2] = fmaxf(v[2] + cb4.z, 0.f); v[3] = fmaxf(v[3] + cb4.w, 0.f);

    float s = v[0] + v[1] + v[2] + v[3];
    float ss = v[0]*v[0] + v[1]*v[1] + v[2]*v[2] + v[3]*v[3];
#pragma unroll
    for (int off = 1; off < 64; off <<= 1) {
        s  += __shfl_xor(s, off);
        ss += __shfl_xor(ss, off);
    }
    const float mu  = s * (1.0f / H_);
    const float var = ss * (1.0f / H_) - mu * mu;
    const float inv = 1.0f / sqrtf(var + 1e-5f);

    float4 g4 = *reinterpret_cast<const float4*>(&g[h0]);
    float4 b4 = *reinterpret_cast<const float4*>(&b[h0]);
    float4 p4 = *reinterpret_cast<const float4*>(&pw[h0]);
    float c = ((v[0]-mu)*inv*g4.x + b4.x) * p4.x
            + ((v[1]-mu)*inv*g4.y + b4.y) * p4.y
            + ((v[2]-mu)*inv*g4.z + b4.z) * p4.z
            + ((v[3]-mu)*inv*g4.w + b4.w) * p4.w;
#pragma unroll
    for (int off = 1; off < 64; off <<= 1) c += __shfl_xor(c, off);

    if (lane == 0) {
        const float ld = c + pb[0];
        const float dv = rintf(expf(ld) - 1.0f);
        int di = (int)dv;
        if (di < 0) di = 0;
        if (mask_at(mraw, t) == 0.0f) di = 0;
        dur[t] = di;
    }
}

// ---------------- per-sequence inclusive cumsum (T=1024) ----------------
__global__ __launch_bounds__(1024) void cumsum_kernel(
    const int* __restrict__ dur, int* __restrict__ cum,
    float* __restrict__ seq_lens_out) {
    __shared__ int s[1024];
    const int n = blockIdx.x, t = threadIdx.x;
    s[t] = dur[n * T_ + t];
    __syncthreads();
    for (int off = 1; off < 1024; off <<= 1) {
        int v = (t >= off) ? s[t - off] : 0;
        __syncthreads();
        s[t] += v;
        __syncthreads();
    }
    cum[n * T_ + t] = s[t];
    if (t == T_ - 1) seq_lens_out[n] = (float)s[t];
}

// ---------------- length-regulator upsample (wave-per-position, nt stores) ----------------
__global__ __launch_bounds__(256) void upsample_kernel(
    const float* __restrict__ seqs, const int* __restrict__ cum,
    float* __restrict__ out) {
    const int wid = blockIdx.x * 4 + (threadIdx.x >> 6);   // n*MAXOUT + p
    const int n = wid >> 12;
    const int p = wid & (MAXOUT - 1);
    const int lane = threadIdx.x & 63;
    const int* c = cum + n * T_;
    const int slen = c[T_ - 1];
    int lo = 0, hi = T_;
    while (lo < hi) {                 // upper_bound: first idx with c[idx] > p (wave-uniform)
        int mid = (lo + hi) >> 1;
        if (c[mid] <= p) lo = mid + 1; else hi = mid;
    }
    const int idx = (lo < T_ - 1) ? lo : (T_ - 1);
    const bool valid = (p < slen);
    const f32x4* src = reinterpret_cast<const f32x4*>(seqs + ((size_t)(n * T_ + idx) * E_));
    f32x4* dst = reinterpret_cast<f32x4*>(out + (size_t)wid * E_);
#pragma unroll
    for (int i = 0; i < 4; ++i) {
        f32x4 v = {0.f, 0.f, 0.f, 0.f};
        if (valid) v = src[lane + 64 * i];
        __builtin_nontemporal_store(v, &dst[lane + 64 * i]);
    }
}

// ---------------- launch ----------------
extern "C" void kernel_launch(void* const* d_in, const int* in_sizes, int n_in,
                              void* d_out, int out_size, void* d_ws, size_t ws_size,
                              hipStream_t stream) {
    const float* seqs = (const float*)d_in[0];
    const float* w1   = (const float*)d_in[1];
    const float* b1   = (const float*)d_in[2];
    const float* g1   = (const float*)d_in[3];
    const float* bb1  = (const float*)d_in[4];
    const float* w2   = (const float*)d_in[5];
    const float* b2   = (const float*)d_in[6];
    const float* g2   = (const float*)d_in[7];
    const float* bb2  = (const float*)d_in[8];
    const float* pw   = (const float*)d_in[9];
    const float* pb   = (const float*)d_in[10];
    const unsigned char* mraw = (const unsigned char*)d_in[11];

    char* wsb = (char*)d_ws;
    half_t* B1p = (half_t*)(wsb + B1P_OFF);
    half_t* B2p = (half_t*)(wsb + B2P_OFF);
    int* dur = (int*)(wsb + DUR_OFF);
    int* cum = (int*)(wsb + CUM_OFF);

    char* outb = (char*)d_out;
    half_t* Y1  = (half_t*)(outb + Y1_OFF);
    half_t* Y2  = (half_t*)(outb + Y2_OFF);
    half_t* A0p = (half_t*)(outb + A0P_OFF);
    half_t* A2p = (half_t*)(outb + A2P_OFF);

    float* out      = (float*)d_out;
    float* slen_out = out + (size_t)N_ * MAXOUT * E_;

    // fused: A-convert (1024 blocks) | W1 (384) | W2 (96)
    prep_all_kernel<<<1504, 256, 0, stream>>>(seqs, mraw, w1, w2, A0p, B1p, B2p);
    gemm_f16_kernel<32><<<dim3(M_ / 128, NJ / 128), 256, 0, stream>>>(A0p, B1p, Y1);
    ln1_kernel<<<M_ / 16, 256, 0, stream>>>(Y1, b1, g1, bb1, mraw, A2p);
    gemm_f16_kernel<8><<<dim3(M_ / 128, NJ / 128), 256, 0, stream>>>(A2p, B2p, Y2);
    ln2_proj_dur_kernel<<<M_ / 4, 256, 0, stream>>>(Y2, b2, g2, bb2, pw, pb, mraw, dur);
    cumsum_kernel<<<N_, 1024, 0, stream>>>(dur, cum, slen_out);
    upsample_kernel<<<(N_ * MAXOUT) / 4, 256, 0, stream>>>(seqs, cum, out);
}